// Round 12
// baseline (397.360 us; speedup 1.0000x reference)
//
#include <hip/hip_runtime.h>

// GraphSAGE 2-layer, N=100000, E=1600000, F=128. Inputs f32; src/dst int32.
//
// CSR build (r11, no per-node global atomics):
//   bcount:  per-block LDS bucket histogram -> bcnt[782]
//   bscan:   1-block scan -> bbase[783], bcur copy
//   bscatter: block-local multisplit -> bucket-contiguous runs in ebuf
//            (r12: EPB 2048, LDS 29KB -> 5 blocks/CU, was 3; atomic-bound)
//   fine_fill2: one block/bucket; pass1 LDS per-node count (coalesced
//            reads) + 128-entry scan -> row[]; pass2 places edges.
// prep_kernel (r12): conv(in_feat->bf16) + both wcat preps in ONE launch.
// Then gather1 -> sbf; gemm1 (infbf->h1bf); gather2; gemm2 -> f32.
//
// ROUND-10/11 LESSONS: global atomicAdd = 32B HBM write-through each
// (count_kernel was 66us); extra dispatch ~5us (4-way gather split +33us).
// ROUND-8 LESSON: per-edge LDS atomics between random load batches
// serialize the wave (78->1200us). Keep gather load stream dependency-free.
//
// mfma_gemm: 512 thr / 256 rows; B(64KB)->LDS via global_load_lds w=16;
// XOR-swizzle byte^=(row&7)<<4 via pre-swizzled SOURCE + swizzled reads
// (rule #21). A prefetch in regs. <66us (never entered r10 top-5).
//
// gather_packed: ~78us = service-rate ceiling for random 256B rows
// (267MB L2-miss traffic @ ~3.9TB/s); batch-16 predication neutral (r4);
// 3 structurally different gathers all land 78us. Treated as floor.
//
// MFMA 16x16x32_bf16 (m89): A lane l: A[m=l&15][k=(l>>4)*8+j];
// B lane l: B[k=(l>>4)*8+j][n=l&15] == W[n][k] row-major; C/D col=l&15,
// row=(l>>4)*4+r.

#define NN 100000
#define NE 1600000
#define F 128

#define NPB 128                                // nodes per bucket (pow2)
#define NPB_BITS 7
#define NBUK ((NN + NPB - 1) / NPB)            // 782 buckets
#define EPB 2048                               // edges per bscatter block
#define NBLK3 ((NE + EPB - 1) / EPB)           // 782
#define EPB2 8192                              // edges per bcount block
#define NBLK2 ((NE + EPB2 - 1) / EPB2)         // 196

#define CONV_BLOCKS 6250                       // NN*F/8/256

// ---- ws layout (bytes) ----
static const size_t BBASE_OFF = 0;          // int[NBUK+1] bucket run bases (+NE cap)
static const size_t BCUR_OFF  = 4000;       // int[NBUK] bscatter cursors
static const size_t BCNT_OFF  = 8000;       // int[NBUK] bucket counts
static const size_t ROW_OFF   = 12000;      // int[NN+1] per-node CSR offsets
static const size_t EDGE_OFF  = 804112;     // int2[NE] final CSR records, 12.8 MB
static const size_t WCAT1_OFF = 13604112;   // bf16[128*256]
static const size_t WCAT2_OFF = 13669648;   // bf16[128*256]
static const size_t SBF_OFF   = 13735184;   // bf16[NN*F]; ALSO ebuf int2[NE] early
static const size_t H1BF_OFF  = 39335184;   // bf16[NN*F]  (infbf then h1bf)
static const size_t WS_NEED   = 64935184;

// ---- fallback layout ----
static const size_t FB_S_OFF = 524288;      // deg f32[NN] @0, s f32[NN*F]

typedef __attribute__((ext_vector_type(8))) short short8;
typedef __attribute__((ext_vector_type(4))) float float4v;

__device__ __forceinline__ float bf2f(unsigned int u16) {
    unsigned int x = u16 << 16;
    float f;
    __builtin_memcpy(&f, &x, 4);
    return f;
}
__device__ __forceinline__ unsigned int f2bf(float f) {
    unsigned int x;
    __builtin_memcpy(&x, &f, 4);
    unsigned int r = x + 0x7FFFu + ((x >> 16) & 1u);
    return r >> 16;
}

__device__ __forceinline__ void gload_lds16(const unsigned short* g, unsigned short* l) {
    __builtin_amdgcn_global_load_lds(
        (const __attribute__((address_space(1))) unsigned int*)(g),
        (__attribute__((address_space(3))) unsigned int*)(l), 16, 0, 0);
}

// ======================= bucket count + scan =======================

__global__ __launch_bounds__(256) void bcount_kernel(const int* __restrict__ dst,
                                                     int* __restrict__ bcnt) {
    __shared__ int hist[NBUK];
    int t = threadIdx.x;
    for (int i = t; i < NBUK; i += 256) hist[i] = 0;
    __syncthreads();
    int base_e = blockIdx.x * EPB2;
#pragma unroll
    for (int i = 0; i < EPB2 / 256; i++) {
        int e = base_e + i * 256 + t;
        if (e < NE) atomicAdd(&hist[dst[e] >> NPB_BITS], 1);
    }
    __syncthreads();
    for (int i = t; i < NBUK; i += 256) {
        int h = hist[i];
        if (h) atomicAdd(&bcnt[i], h);
    }
}

// 1-block exclusive scan over bcnt[NBUK] (NBUK=782 <= 256*4).
__global__ __launch_bounds__(256) void bscan_kernel(const int* __restrict__ bcnt,
                                                    int* __restrict__ bbase,
                                                    int* __restrict__ bcur) {
    __shared__ int ts[256];
    int t = threadIdx.x;
    int v[4];
    int base = t * 4;
    int s = 0;
#pragma unroll
    for (int i = 0; i < 4; i++) {
        int idx = base + i;
        v[i] = (idx < NBUK) ? bcnt[idx] : 0;
        s += v[i];
    }
    ts[t] = s;
    __syncthreads();
    for (int off = 1; off < 256; off <<= 1) {
        int u = (t >= off) ? ts[t - off] : 0;
        __syncthreads();
        ts[t] += u;
        __syncthreads();
    }
    int run = ts[t] - s;   // exclusive prefix of this 4-chunk
#pragma unroll
    for (int i = 0; i < 4; i++) {
        int idx = base + i;
        if (idx < NBUK) { bbase[idx] = run; bcur[idx] = run; }
        run += v[i];
    }
    if (t == 255) bbase[NBUK] = run;   // == NE
}

// ======================= bucket multisplit =======================
// rec.x = src(17b) | dst_local(7b)<<17 ; rec.y = w bits.
// EPB=2048: LDS = 16KB rec + 4KB bid + 9.4KB hist/gbase/cur = 29.4KB
// -> 5 blocks/CU (was 3 at EPB=4096/49KB). Kernel is LDS-atomic-bound.
__global__ __launch_bounds__(256) void bscatter(const int* __restrict__ src,
                                                const int* __restrict__ dst,
                                                const float* __restrict__ w,
                                                int* __restrict__ bcur,
                                                int2* __restrict__ ebuf) {
    __shared__ int2 rec[EPB];
    __shared__ unsigned short bid[EPB];
    __shared__ int hist[NBUK];
    __shared__ int gbase[NBUK];
    __shared__ int cur[NBUK];

    int t = threadIdx.x;
    for (int i = t; i < NBUK; i += 256) { hist[i] = 0; cur[i] = 0; }
    __syncthreads();

    int base_e = blockIdx.x * EPB;
#pragma unroll
    for (int i = 0; i < EPB / 256; i++) {
        int idx = i * 256 + t;
        int e = base_e + idx;
        if (e < NE) {
            int d = dst[e];
            int b = d >> NPB_BITS;
            int2 r;
            r.x = src[e] | ((d & (NPB - 1)) << 17);
            r.y = __float_as_int(w[e]);
            rec[idx] = r;
            bid[idx] = (unsigned short)b;
            atomicAdd(&hist[b], 1);
        } else {
            bid[idx] = 0xFFFFu;
        }
    }
    __syncthreads();

    for (int i = t; i < NBUK; i += 256)
        if (hist[i] > 0) gbase[i] = atomicAdd(&bcur[i], hist[i]);
    __syncthreads();

#pragma unroll
    for (int i = 0; i < EPB / 256; i++) {
        int idx = i * 256 + t;
        int b = bid[idx];
        if (b != 0xFFFFu) {
            int r = atomicAdd(&cur[b], 1);
            ebuf[gbase[b] + r] = rec[idx];
        }
    }
}

// ======================= fine fill + per-node CSR (no global count) ====
// One block per bucket. Pass1: LDS per-node count over the bucket's edge
// run (coalesced reads). 128-entry LDS scan -> row[] (global per-node CSR
// offsets). Pass2: place edges via LDS cursors inside the bucket's ~16KB
// L2-resident window.
__global__ __launch_bounds__(256) void fine_fill2(const int* __restrict__ bbase,
                                                  const int2* __restrict__ ebuf,
                                                  int* __restrict__ row,
                                                  int2* __restrict__ edge) {
    __shared__ int lcnt[NPB];
    __shared__ int ts[NPB];
    __shared__ int lcur[NPB];
    int b = blockIdx.x;
    int t = threadIdx.x;
    int n0 = b * NPB;

    if (t < NPB) lcnt[t] = 0;
    __syncthreads();

    int beg = bbase[b], end = bbase[b + 1];

    // pass 1: per-node counts
    for (int e = beg + t; e < end; e += 256) {
        int dl = (ebuf[e].x >> 17) & (NPB - 1);
        atomicAdd(&lcnt[dl], 1);
    }
    __syncthreads();

    // 128-entry inclusive scan (threads 0..127 active; all hit barriers)
    int v = (t < NPB) ? lcnt[t] : 0;
    if (t < NPB) ts[t] = v;
    __syncthreads();
    for (int off = 1; off < NPB; off <<= 1) {
        int u = (t >= off && t < NPB) ? ts[t - off] : 0;
        __syncthreads();
        if (t < NPB) ts[t] += u;
        __syncthreads();
    }
    if (t < NPB) {
        int o = beg + ts[t] - v;       // exclusive prefix -> node offset
        lcur[t] = o;
        int n = n0 + t;
        if (n <= NN) row[n] = o;       // last bucket's t=32 writes row[NN]=NE
    }
    __syncthreads();

    // pass 2: place edges
    for (int e = beg + t; e < end; e += 256) {
        int2 r = ebuf[e];
        int dl = (r.x >> 17) & (NPB - 1);
        int pos = atomicAdd(&lcur[dl], 1);
        int2 o;
        o.x = r.x & 0x1FFFF;
        o.y = r.y;
        edge[pos] = o;
    }
}

// ======================= fused prep: conv + both wcat =======================
// blocks [0, CONV_BLOCKS): in_feat f32 -> bf16 (8 elems/thread).
// blocks [CONV_BLOCKS, CONV_BLOCKS+256): wcat1/wcat2 build (1 elem/thread).
__global__ __launch_bounds__(256) void prep_kernel(const float* __restrict__ in,
                                                   unsigned short* __restrict__ outbf,
                                                   const float* __restrict__ Ws1,
                                                   const float* __restrict__ Wn1,
                                                   const float* __restrict__ Ws2,
                                                   const float* __restrict__ Wn2,
                                                   unsigned short* __restrict__ wcat1,
                                                   unsigned short* __restrict__ wcat2) {
    if (blockIdx.x < CONV_BLOCKS) {
        size_t base = ((size_t)blockIdx.x * 256 + threadIdx.x) * 8;
        float4 a = *(const float4*)(in + base);
        float4 b = *(const float4*)(in + base + 4);
        uint4 p;
        p.x = f2bf(a.x) | (f2bf(a.y) << 16);
        p.y = f2bf(a.z) | (f2bf(a.w) << 16);
        p.z = f2bf(b.x) | (f2bf(b.y) << 16);
        p.w = f2bf(b.z) | (f2bf(b.w) << 16);
        *(uint4*)(outbf + base) = p;
    } else {
        int idx = (blockIdx.x - CONV_BLOCKS) * 256 + threadIdx.x;   // 65536
        int which = idx >> 15;
        int j = idx & 32767;
        int n = j >> 8, k = j & 255;
        const float* Ws = which ? Ws2 : Ws1;
        const float* Wn = which ? Wn2 : Wn1;
        float v = (k < 128) ? Ws[n * 128 + k] : Wn[n * 128 + (k - 128)];
        unsigned short* o = which ? wcat2 : wcat1;
        o[j] = (unsigned short)f2bf(v);
    }
}

// ======================= gather (packed bf16, int2 edges) =======================
__global__ __launch_bounds__(256) void gather_packed(const unsigned short* __restrict__ h,
                                                     const int* __restrict__ row,
                                                     const int2* __restrict__ edge,
                                                     unsigned short* __restrict__ sbf) {
    int t = threadIdx.x;
    int lane = t & 63;
    int n = blockIdx.x * 4 + (t >> 6);           // NN divisible by 4
    int beg = __builtin_amdgcn_readfirstlane(row[n]);
    int end = __builtin_amdgcn_readfirstlane(row[n + 1]);
    const unsigned int* hp = (const unsigned int*)h;   // row stride 64 uints

    float ax = 0.0f, ay = 0.0f;
    int e = beg;
    for (; e + 7 < end; e += 8) {
        int2 m[8];
#pragma unroll
        for (int i = 0; i < 8; i++) m[i] = edge[e + i];
        unsigned int p[8];
#pragma unroll
        for (int i = 0; i < 8; i++) p[i] = hp[(size_t)m[i].x * 64 + lane];
#pragma unroll
        for (int i = 0; i < 8; i++) {
            float wf = __int_as_float(m[i].y);
            ax += wf * bf2f(p[i] & 0xFFFFu);
            ay += wf * bf2f(p[i] >> 16);
        }
    }
    for (; e < end; e++) {
        int2 m0 = edge[e];
        unsigned int p0 = hp[(size_t)m0.x * 64 + lane];
        float wf = __int_as_float(m0.y);
        ax += wf * bf2f(p0 & 0xFFFFu);
        ay += wf * bf2f(p0 >> 16);
    }
    float invd = 1.0f / fmaxf((float)(end - beg), 1.0f);
    unsigned int outp = f2bf(ax * invd) | (f2bf(ay * invd) << 16);
    ((unsigned int*)sbf)[(size_t)n * 64 + lane] = outp;
}

// ======================= MFMA GEMM =======================
// 512 threads, 256 rows/block. B (wcat 64KB) -> LDS via global_load_lds,
// XOR-swizzled (byte ^= (row&7)<<4) through pre-swizzled source + swizzled
// reads. A per-half prefetch in regs. 2 blocks/CU (LDS) x 8 waves = 16 waves/CU.

__global__ __launch_bounds__(512, 4) void mfma_gemm(
    const unsigned short* self_bf,               // bf16 [NN,F] (may alias out_bf)
    const unsigned short* __restrict__ sbf,      // bf16 [NN,F] normalized neigh
    const unsigned short* __restrict__ wcat,     // bf16 [128][256]
    const float* __restrict__ bias,              // f32 [128]
    unsigned short* out_bf,                      // layer1: relu+bf16 (or null)
    float* __restrict__ out_f32)                 // layer2: f32 (or null)
{
    __shared__ unsigned short Bs[128][256];      // 64 KB: full wcat copy (swizzled)

    int t = threadIdx.x;                         // 0..511
    int l = t & 63;
    int w = t >> 6;                              // 0..7
    int base = blockIdx.x * 256;
    int lane16 = l & 15;
    int quad = l >> 4;
    int swz = (lane16 & 7) << 3;                 // ushort-units XOR for B reads

    // Stage wcat -> LDS. LDS dest strictly linear (lane-consecutive 16B);
    // source address carries the inverse swizzle.
    unsigned short* lbase = &Bs[0][0];
#pragma unroll
    for (int i = 0; i < 8; i++) {
        int idx = i * 512 + t;                   // 16B chunk index, 4096 total
        int r = idx >> 5;                        // row (512B = 32 chunks)
        int cb = (idx & 31) << 4;                // byte-in-row, 16B aligned
        int sb = cb ^ ((r & 7) << 4);            // pre-swizzled source byte
        gload_lds16(wcat + r * 256 + (sb >> 1), lbase + idx * 8);
    }

    // Each wave owns rows [base+w*32, base+w*32+32).
    int r0 = base + w * 32 + lane16;
    int r1 = r0 + 16;
    int r0c = min(r0, NN - 1);
    int r1c = min(r1, NN - 1);

    float4v acc0[8], acc1[8];
#pragma unroll
    for (int ct = 0; ct < 8; ct++) {
        acc0[ct] = (float4v){0.f, 0.f, 0.f, 0.f};
        acc1[ct] = (float4v){0.f, 0.f, 0.f, 0.f};
    }

    __syncthreads();                             // drains global_load_lds (vmcnt 0)

#pragma unroll
    for (int half = 0; half < 2; half++) {
        const unsigned short* srcb = (half == 0) ? self_bf : sbf;
        const unsigned short* p0 = srcb + (size_t)r0c * F + quad * 8;
        const unsigned short* p1 = srcb + (size_t)r1c * F + quad * 8;
        short8 Ah0[4], Ah1[4];
#pragma unroll
        for (int kk = 0; kk < 4; kk++) {
            Ah0[kk] = *(const short8*)(p0 + kk * 32);
            Ah1[kk] = *(const short8*)(p1 + kk * 32);
        }
#pragma unroll
        for (int kk = 0; kk < 4; kk++) {
#pragma unroll
            for (int ct = 0; ct < 8; ct++) {
                int r = ct * 16 + lane16;
                int col = half * 128 + kk * 32 + quad * 8;
                short8 b = *(const short8*)(lbase + (size_t)r * 256 + (col ^ swz));
                acc0[ct] = __builtin_amdgcn_mfma_f32_16x16x32_bf16(Ah0[kk], b, acc0[ct], 0, 0, 0);
                acc1[ct] = __builtin_amdgcn_mfma_f32_16x16x32_bf16(Ah1[kk], b, acc1[ct], 0, 0, 0);
            }
        }
    }

    int rowb0 = base + w * 32 + quad * 4;
    int rowb1 = rowb0 + 16;
#pragma unroll
    for (int ct = 0; ct < 8; ct++) {
        int col = ct * 16 + lane16;
        float bc = bias[col];
#pragma unroll
        for (int r = 0; r < 4; r++) {
            int g0 = rowb0 + r, g1 = rowb1 + r;
            float v0 = acc0[ct][r] + bc;
            float v1 = acc1[ct][r] + bc;
            if (out_bf) {
                v0 = fmaxf(v0, 0.0f);
                v1 = fmaxf(v1, 0.0f);
                if (g0 < NN) out_bf[(size_t)g0 * F + col] = (unsigned short)f2bf(v0);
                if (g1 < NN) out_bf[(size_t)g1 * F + col] = (unsigned short)f2bf(v1);
            } else {
                if (g0 < NN) out_f32[(size_t)g0 * F + col] = v0;
                if (g1 < NN) out_f32[(size_t)g1 * F + col] = v1;
            }
        }
    }
}

// ======================= fallback (f32 atomic path) =======================

__global__ __launch_bounds__(256) void scatter_kernel(const float* __restrict__ h,
                                                      const float* __restrict__ w,
                                                      const int* __restrict__ src,
                                                      const int* __restrict__ dst,
                                                      float* __restrict__ s,
                                                      float* __restrict__ deg,
                                                      int add_deg) {
    int e = blockIdx.x * 4 + (threadIdx.x >> 6);
    int lane = threadIdx.x & 63;
    int sn = src[e];
    int dn = dst[e];
    float wf = w[e];
    float2 p = *(const float2*)(h + (size_t)sn * F + lane * 2);
    float* sp = s + (size_t)dn * F + lane * 2;
    unsafeAtomicAdd(sp,     wf * p.x);
    unsafeAtomicAdd(sp + 1, wf * p.y);
    if (add_deg && lane == 0) unsafeAtomicAdd(&deg[dn], 1.0f);
}

__global__ __launch_bounds__(256) void sage_gemm(const float* h,
                                                 const float* __restrict__ s,
                                                 const float* deg,
                                                 const float* __restrict__ Ws,
                                                 const float* __restrict__ bias,
                                                 const float* __restrict__ Wn,
                                                 float* out,
                                                 int relu) {
    __shared__ float xs[16][F];
    __shared__ float invd[16];
    int t = threadIdx.x;
    int j = t & 127;
    int g = t >> 7;
    int base = blockIdx.x * 16;
    for (int idx = t; idx < 16 * 32; idx += 256) {
        int n = idx >> 5, kq = idx & 31;
        *(float4*)&xs[n][kq * 4] = *(const float4*)(h + (size_t)(base + n) * F + kq * 4);
    }
    if (t < 16) invd[t] = deg ? 1.0f / fmaxf(deg[base + t], 1.0f) : 1.0f;
    __syncthreads();
    float acc[8];
#pragma unroll
    for (int i = 0; i < 8; i++) acc[i] = 0.0f;
    for (int kc = 0; kc < F; kc += 4) {
        float4 wv = *(const float4*)(Ws + j * F + kc);
#pragma unroll
        for (int i = 0; i < 8; i++) {
            const float* xr = &xs[g * 8 + i][kc];
            acc[i] += xr[0] * wv.x + xr[1] * wv.y + xr[2] * wv.z + xr[3] * wv.w;
        }
    }
    __syncthreads();
    for (int idx = t; idx < 16 * 32; idx += 256) {
        int n = idx >> 5, kq = idx & 31;
        float4 sv = *(const float4*)(s + (size_t)(base + n) * F + kq * 4);
        float iv = invd[n];
        xs[n][kq * 4]     = sv.x * iv;
        xs[n][kq * 4 + 1] = sv.y * iv;
        xs[n][kq * 4 + 2] = sv.z * iv;
        xs[n][kq * 4 + 3] = sv.w * iv;
    }
    __syncthreads();
    for (int kc = 0; kc < F; kc += 4) {
        float4 wv = *(const float4*)(Wn + j * F + kc);
#pragma unroll
        for (int i = 0; i < 8; i++) {
            const float* xr = &xs[g * 8 + i][kc];
            acc[i] += xr[0] * wv.x + xr[1] * wv.y + xr[2] * wv.z + xr[3] * wv.w;
        }
    }
    float bj = bias[j];
#pragma unroll
    for (int i = 0; i < 8; i++) {
        int n = base + g * 8 + i;
        float v = acc[i] + bj;
        if (relu) v = fmaxf(v, 0.0f);
        out[(size_t)n * F + j] = v;
    }
}

extern "C" void kernel_launch(void* const* d_in, const int* in_sizes, int n_in,
                              void* d_out, int out_size, void* d_ws, size_t ws_size,
                              hipStream_t stream) {
    const float* in_feat = (const float*)d_in[0];
    const float* weights = (const float*)d_in[1];
    const int* src = (const int*)d_in[2];
    const int* dst = (const int*)d_in[3];
    const float* Ws1 = (const float*)d_in[4];
    const float* b1  = (const float*)d_in[5];
    const float* Wn1 = (const float*)d_in[6];
    const float* Ws2 = (const float*)d_in[7];
    const float* b2  = (const float*)d_in[8];
    const float* Wn2 = (const float*)d_in[9];
    float* out = (float*)d_out;

    if (ws_size >= WS_NEED) {
        int* bbase  = (int*)((char*)d_ws + BBASE_OFF);
        int* bcur   = (int*)((char*)d_ws + BCUR_OFF);
        int* bcnt   = (int*)((char*)d_ws + BCNT_OFF);
        int* row    = (int*)((char*)d_ws + ROW_OFF);
        int2* edge  = (int2*)((char*)d_ws + EDGE_OFF);
        unsigned short* wcat1 = (unsigned short*)((char*)d_ws + WCAT1_OFF);
        unsigned short* wcat2 = (unsigned short*)((char*)d_ws + WCAT2_OFF);
        unsigned short* sbf   = (unsigned short*)((char*)d_ws + SBF_OFF);
        int2* ebuf  = (int2*)((char*)d_ws + SBF_OFF);   // aliases sbf (dead until gather1)
        unsigned short* hbf   = (unsigned short*)((char*)d_ws + H1BF_OFF); // infbf -> h1bf

        hipMemsetAsync(bcnt, 0, NBUK * sizeof(int), stream);
        bcount_kernel<<<NBLK2, 256, 0, stream>>>(dst, bcnt);
        bscan_kernel<<<1, 256, 0, stream>>>(bcnt, bbase, bcur);
        bscatter<<<NBLK3, 256, 0, stream>>>(src, dst, weights, bcur, ebuf);
        fine_fill2<<<NBUK, 256, 0, stream>>>(bbase, ebuf, row, edge);
        prep_kernel<<<CONV_BLOCKS + 256, 256, 0, stream>>>(in_feat, hbf,
                                                           Ws1, Wn1, Ws2, Wn2,
                                                           wcat1, wcat2);

        // layer 1 (gemm1 in-place over hbf: infbf -> h1bf)
        gather_packed<<<NN / 4, 256, 0, stream>>>(hbf, row, edge, sbf);
        mfma_gemm<<<(NN + 255) / 256, 512, 0, stream>>>(hbf, sbf, wcat1, b1, hbf, nullptr);
        // layer 2
        gather_packed<<<NN / 4, 256, 0, stream>>>(hbf, row, edge, sbf);
        mfma_gemm<<<(NN + 255) / 256, 512, 0, stream>>>(hbf, sbf, wcat2, b2, nullptr, out);
    } else {
        float* deg = (float*)d_ws;
        float* s   = (float*)((char*)d_ws + FB_S_OFF);
        hipMemsetAsync(d_ws, 0, FB_S_OFF + (size_t)NN * F * 4, stream);
        scatter_kernel<<<NE / 4, 256, 0, stream>>>(in_feat, weights, src, dst, s, deg, 1);
        sage_gemm<<<NN / 16, 256, 0, stream>>>(in_feat, s, deg, Ws1, b1, Wn1, out, 1);
        hipMemsetAsync(s, 0, (size_t)NN * F * 4, stream);
        scatter_kernel<<<NE / 4, 256, 0, stream>>>(out, weights, src, dst, s, deg, 0);
        sage_gemm<<<NN / 16, 256, 0, stream>>>(out, s, deg, Ws2, b2, Wn2, out, 0);
    }
}

// Round 13
// 380.295 us; speedup vs baseline: 1.0449x; 1.0449x over previous
//
#include <hip/hip_runtime.h>

// GraphSAGE 2-layer, N=100000, E=1600000, F=128. Inputs f32; src/dst int32.
//
// CSR build (r11, no per-node global atomics):
//   bcount:  per-block LDS bucket histogram -> bcnt[782]
//   bscan:   1-block scan -> bbase[783], bcur copy
//   bscatter: block-local multisplit -> bucket-contiguous runs in ebuf
//            EPB=4096 (r13: reverted from r12's 2048 -- halving EPB doubled
//            the per-block NBUK-proportional fixed cost (LDS init + gbase
//            sweep), +11us regression; kernel was NOT concurrency-bound)
//   fine_fill2: one block/bucket; pass1 LDS per-node count (coalesced
//            reads) + 128-entry scan -> row[]; pass2 places edges.
// prep_kernel: conv(in_feat->bf16) + both wcat preps in ONE launch (kept).
// Then gather1 -> sbf; gemm1 (infbf->h1bf); gather2; gemm2 -> f32.
//
// ROUND-10/11/12 LESSONS: global atomicAdd = 32B HBM write-through each
// (count_kernel was 66us); extra dispatch ~5us; per-block fixed costs
// scale with grid -- don't shrink work-per-block of kernels with large
// per-block setup. ROUND-8: per-edge LDS atomics between random load
// batches serialize the wave (78->1200us).
//
// mfma_gemm: 512 thr / 256 rows; B(64KB)->LDS via global_load_lds w=16;
// XOR-swizzle byte^=(row&7)<<4 via pre-swizzled SOURCE + swizzled reads
// (rule #21). A prefetch in regs. <66us (never entered r10 top-5).
//
// gather_packed: ~78us = service-rate ceiling for random 256B rows
// (267MB L2-miss traffic @ ~3.9TB/s); batch-16 predication neutral (r4);
// 3 structurally different gathers all land 78us. Treated as floor.
//
// MFMA 16x16x32_bf16 (m89): A lane l: A[m=l&15][k=(l>>4)*8+j];
// B lane l: B[k=(l>>4)*8+j][n=l&15] == W[n][k] row-major; C/D col=l&15,
// row=(l>>4)*4+r.

#define NN 100000
#define NE 1600000
#define F 128

#define NPB 128                                // nodes per bucket (pow2)
#define NPB_BITS 7
#define NBUK ((NN + NPB - 1) / NPB)            // 782 buckets
#define EPB 4096                               // edges per bscatter block
#define NBLK3 ((NE + EPB - 1) / EPB)           // 391
#define EPB2 8192                              // edges per bcount block
#define NBLK2 ((NE + EPB2 - 1) / EPB2)         // 196

#define CONV_BLOCKS 6250                       // NN*F/8/256

// ---- ws layout (bytes) ----
static const size_t BBASE_OFF = 0;          // int[NBUK+1] bucket run bases (+NE cap)
static const size_t BCUR_OFF  = 4000;       // int[NBUK] bscatter cursors
static const size_t BCNT_OFF  = 8000;       // int[NBUK] bucket counts
static const size_t ROW_OFF   = 12000;      // int[NN+1] per-node CSR offsets
static const size_t EDGE_OFF  = 804112;     // int2[NE] final CSR records, 12.8 MB
static const size_t WCAT1_OFF = 13604112;   // bf16[128*256]
static const size_t WCAT2_OFF = 13669648;   // bf16[128*256]
static const size_t SBF_OFF   = 13735184;   // bf16[NN*F]; ALSO ebuf int2[NE] early
static const size_t H1BF_OFF  = 39335184;   // bf16[NN*F]  (infbf then h1bf)
static const size_t WS_NEED   = 64935184;

// ---- fallback layout ----
static const size_t FB_S_OFF = 524288;      // deg f32[NN] @0, s f32[NN*F]

typedef __attribute__((ext_vector_type(8))) short short8;
typedef __attribute__((ext_vector_type(4))) float float4v;

__device__ __forceinline__ float bf2f(unsigned int u16) {
    unsigned int x = u16 << 16;
    float f;
    __builtin_memcpy(&f, &x, 4);
    return f;
}
__device__ __forceinline__ unsigned int f2bf(float f) {
    unsigned int x;
    __builtin_memcpy(&x, &f, 4);
    unsigned int r = x + 0x7FFFu + ((x >> 16) & 1u);
    return r >> 16;
}

__device__ __forceinline__ void gload_lds16(const unsigned short* g, unsigned short* l) {
    __builtin_amdgcn_global_load_lds(
        (const __attribute__((address_space(1))) unsigned int*)(g),
        (__attribute__((address_space(3))) unsigned int*)(l), 16, 0, 0);
}

// ======================= bucket count + scan =======================

__global__ __launch_bounds__(256) void bcount_kernel(const int* __restrict__ dst,
                                                     int* __restrict__ bcnt) {
    __shared__ int hist[NBUK];
    int t = threadIdx.x;
    for (int i = t; i < NBUK; i += 256) hist[i] = 0;
    __syncthreads();
    int base_e = blockIdx.x * EPB2;
#pragma unroll
    for (int i = 0; i < EPB2 / 256; i++) {
        int e = base_e + i * 256 + t;
        if (e < NE) atomicAdd(&hist[dst[e] >> NPB_BITS], 1);
    }
    __syncthreads();
    for (int i = t; i < NBUK; i += 256) {
        int h = hist[i];
        if (h) atomicAdd(&bcnt[i], h);
    }
}

// 1-block exclusive scan over bcnt[NBUK] (NBUK=782 <= 256*4).
__global__ __launch_bounds__(256) void bscan_kernel(const int* __restrict__ bcnt,
                                                    int* __restrict__ bbase,
                                                    int* __restrict__ bcur) {
    __shared__ int ts[256];
    int t = threadIdx.x;
    int v[4];
    int base = t * 4;
    int s = 0;
#pragma unroll
    for (int i = 0; i < 4; i++) {
        int idx = base + i;
        v[i] = (idx < NBUK) ? bcnt[idx] : 0;
        s += v[i];
    }
    ts[t] = s;
    __syncthreads();
    for (int off = 1; off < 256; off <<= 1) {
        int u = (t >= off) ? ts[t - off] : 0;
        __syncthreads();
        ts[t] += u;
        __syncthreads();
    }
    int run = ts[t] - s;   // exclusive prefix of this 4-chunk
#pragma unroll
    for (int i = 0; i < 4; i++) {
        int idx = base + i;
        if (idx < NBUK) { bbase[idx] = run; bcur[idx] = run; }
        run += v[i];
    }
    if (t == 255) bbase[NBUK] = run;   // == NE
}

// ======================= bucket multisplit =======================
// rec.x = src(17b) | dst_local(7b)<<17 ; rec.y = w bits.
__global__ __launch_bounds__(256) void bscatter(const int* __restrict__ src,
                                                const int* __restrict__ dst,
                                                const float* __restrict__ w,
                                                int* __restrict__ bcur,
                                                int2* __restrict__ ebuf) {
    __shared__ int2 rec[EPB];
    __shared__ unsigned short bid[EPB];
    __shared__ int hist[NBUK];
    __shared__ int gbase[NBUK];
    __shared__ int cur[NBUK];

    int t = threadIdx.x;
    for (int i = t; i < NBUK; i += 256) { hist[i] = 0; cur[i] = 0; }
    __syncthreads();

    int base_e = blockIdx.x * EPB;
#pragma unroll
    for (int i = 0; i < EPB / 256; i++) {
        int idx = i * 256 + t;
        int e = base_e + idx;
        if (e < NE) {
            int d = dst[e];
            int b = d >> NPB_BITS;
            int2 r;
            r.x = src[e] | ((d & (NPB - 1)) << 17);
            r.y = __float_as_int(w[e]);
            rec[idx] = r;
            bid[idx] = (unsigned short)b;
            atomicAdd(&hist[b], 1);
        } else {
            bid[idx] = 0xFFFFu;
        }
    }
    __syncthreads();

    for (int i = t; i < NBUK; i += 256)
        if (hist[i] > 0) gbase[i] = atomicAdd(&bcur[i], hist[i]);
    __syncthreads();

#pragma unroll
    for (int i = 0; i < EPB / 256; i++) {
        int idx = i * 256 + t;
        int b = bid[idx];
        if (b != 0xFFFFu) {
            int r = atomicAdd(&cur[b], 1);
            ebuf[gbase[b] + r] = rec[idx];
        }
    }
}

// ======================= fine fill + per-node CSR (no global count) ====
// One block per bucket. Pass1: LDS per-node count over the bucket's edge
// run (coalesced reads). 128-entry LDS scan -> row[] (global per-node CSR
// offsets). Pass2: place edges via LDS cursors inside the bucket's ~16KB
// L2-resident window.
__global__ __launch_bounds__(256) void fine_fill2(const int* __restrict__ bbase,
                                                  const int2* __restrict__ ebuf,
                                                  int* __restrict__ row,
                                                  int2* __restrict__ edge) {
    __shared__ int lcnt[NPB];
    __shared__ int ts[NPB];
    __shared__ int lcur[NPB];
    int b = blockIdx.x;
    int t = threadIdx.x;
    int n0 = b * NPB;

    if (t < NPB) lcnt[t] = 0;
    __syncthreads();

    int beg = bbase[b], end = bbase[b + 1];

    // pass 1: per-node counts
    for (int e = beg + t; e < end; e += 256) {
        int dl = (ebuf[e].x >> 17) & (NPB - 1);
        atomicAdd(&lcnt[dl], 1);
    }
    __syncthreads();

    // 128-entry inclusive scan (threads 0..127 active; all hit barriers)
    int v = (t < NPB) ? lcnt[t] : 0;
    if (t < NPB) ts[t] = v;
    __syncthreads();
    for (int off = 1; off < NPB; off <<= 1) {
        int u = (t >= off && t < NPB) ? ts[t - off] : 0;
        __syncthreads();
        if (t < NPB) ts[t] += u;
        __syncthreads();
    }
    if (t < NPB) {
        int o = beg + ts[t] - v;       // exclusive prefix -> node offset
        lcur[t] = o;
        int n = n0 + t;
        if (n <= NN) row[n] = o;       // last bucket's t=32 writes row[NN]=NE
    }
    __syncthreads();

    // pass 2: place edges
    for (int e = beg + t; e < end; e += 256) {
        int2 r = ebuf[e];
        int dl = (r.x >> 17) & (NPB - 1);
        int pos = atomicAdd(&lcur[dl], 1);
        int2 o;
        o.x = r.x & 0x1FFFF;
        o.y = r.y;
        edge[pos] = o;
    }
}

// ======================= fused prep: conv + both wcat =======================
// blocks [0, CONV_BLOCKS): in_feat f32 -> bf16 (8 elems/thread).
// blocks [CONV_BLOCKS, CONV_BLOCKS+256): wcat1/wcat2 build (1 elem/thread).
__global__ __launch_bounds__(256) void prep_kernel(const float* __restrict__ in,
                                                   unsigned short* __restrict__ outbf,
                                                   const float* __restrict__ Ws1,
                                                   const float* __restrict__ Wn1,
                                                   const float* __restrict__ Ws2,
                                                   const float* __restrict__ Wn2,
                                                   unsigned short* __restrict__ wcat1,
                                                   unsigned short* __restrict__ wcat2) {
    if (blockIdx.x < CONV_BLOCKS) {
        size_t base = ((size_t)blockIdx.x * 256 + threadIdx.x) * 8;
        float4 a = *(const float4*)(in + base);
        float4 b = *(const float4*)(in + base + 4);
        uint4 p;
        p.x = f2bf(a.x) | (f2bf(a.y) << 16);
        p.y = f2bf(a.z) | (f2bf(a.w) << 16);
        p.z = f2bf(b.x) | (f2bf(b.y) << 16);
        p.w = f2bf(b.z) | (f2bf(b.w) << 16);
        *(uint4*)(outbf + base) = p;
    } else {
        int idx = (blockIdx.x - CONV_BLOCKS) * 256 + threadIdx.x;   // 65536
        int which = idx >> 15;
        int j = idx & 32767;
        int n = j >> 8, k = j & 255;
        const float* Ws = which ? Ws2 : Ws1;
        const float* Wn = which ? Wn2 : Wn1;
        float v = (k < 128) ? Ws[n * 128 + k] : Wn[n * 128 + (k - 128)];
        unsigned short* o = which ? wcat2 : wcat1;
        o[j] = (unsigned short)f2bf(v);
    }
}

// ======================= gather (packed bf16, int2 edges) =======================
__global__ __launch_bounds__(256) void gather_packed(const unsigned short* __restrict__ h,
                                                     const int* __restrict__ row,
                                                     const int2* __restrict__ edge,
                                                     unsigned short* __restrict__ sbf) {
    int t = threadIdx.x;
    int lane = t & 63;
    int n = blockIdx.x * 4 + (t >> 6);           // NN divisible by 4
    int beg = __builtin_amdgcn_readfirstlane(row[n]);
    int end = __builtin_amdgcn_readfirstlane(row[n + 1]);
    const unsigned int* hp = (const unsigned int*)h;   // row stride 64 uints

    float ax = 0.0f, ay = 0.0f;
    int e = beg;
    for (; e + 7 < end; e += 8) {
        int2 m[8];
#pragma unroll
        for (int i = 0; i < 8; i++) m[i] = edge[e + i];
        unsigned int p[8];
#pragma unroll
        for (int i = 0; i < 8; i++) p[i] = hp[(size_t)m[i].x * 64 + lane];
#pragma unroll
        for (int i = 0; i < 8; i++) {
            float wf = __int_as_float(m[i].y);
            ax += wf * bf2f(p[i] & 0xFFFFu);
            ay += wf * bf2f(p[i] >> 16);
        }
    }
    for (; e < end; e++) {
        int2 m0 = edge[e];
        unsigned int p0 = hp[(size_t)m0.x * 64 + lane];
        float wf = __int_as_float(m0.y);
        ax += wf * bf2f(p0 & 0xFFFFu);
        ay += wf * bf2f(p0 >> 16);
    }
    float invd = 1.0f / fmaxf((float)(end - beg), 1.0f);
    unsigned int outp = f2bf(ax * invd) | (f2bf(ay * invd) << 16);
    ((unsigned int*)sbf)[(size_t)n * 64 + lane] = outp;
}

// ======================= MFMA GEMM =======================
// 512 threads, 256 rows/block. B (wcat 64KB) -> LDS via global_load_lds,
// XOR-swizzled (byte ^= (row&7)<<4) through pre-swizzled source + swizzled
// reads. A per-half prefetch in regs. 2 blocks/CU (LDS) x 8 waves = 16 waves/CU.

__global__ __launch_bounds__(512, 4) void mfma_gemm(
    const unsigned short* self_bf,               // bf16 [NN,F] (may alias out_bf)
    const unsigned short* __restrict__ sbf,      // bf16 [NN,F] normalized neigh
    const unsigned short* __restrict__ wcat,     // bf16 [128][256]
    const float* __restrict__ bias,              // f32 [128]
    unsigned short* out_bf,                      // layer1: relu+bf16 (or null)
    float* __restrict__ out_f32)                 // layer2: f32 (or null)
{
    __shared__ unsigned short Bs[128][256];      // 64 KB: full wcat copy (swizzled)

    int t = threadIdx.x;                         // 0..511
    int l = t & 63;
    int w = t >> 6;                              // 0..7
    int base = blockIdx.x * 256;
    int lane16 = l & 15;
    int quad = l >> 4;
    int swz = (lane16 & 7) << 3;                 // ushort-units XOR for B reads

    // Stage wcat -> LDS. LDS dest strictly linear (lane-consecutive 16B);
    // source address carries the inverse swizzle.
    unsigned short* lbase = &Bs[0][0];
#pragma unroll
    for (int i = 0; i < 8; i++) {
        int idx = i * 512 + t;                   // 16B chunk index, 4096 total
        int r = idx >> 5;                        // row (512B = 32 chunks)
        int cb = (idx & 31) << 4;                // byte-in-row, 16B aligned
        int sb = cb ^ ((r & 7) << 4);            // pre-swizzled source byte
        gload_lds16(wcat + r * 256 + (sb >> 1), lbase + idx * 8);
    }

    // Each wave owns rows [base+w*32, base+w*32+32).
    int r0 = base + w * 32 + lane16;
    int r1 = r0 + 16;
    int r0c = min(r0, NN - 1);
    int r1c = min(r1, NN - 1);

    float4v acc0[8], acc1[8];
#pragma unroll
    for (int ct = 0; ct < 8; ct++) {
        acc0[ct] = (float4v){0.f, 0.f, 0.f, 0.f};
        acc1[ct] = (float4v){0.f, 0.f, 0.f, 0.f};
    }

    __syncthreads();                             // drains global_load_lds (vmcnt 0)

#pragma unroll
    for (int half = 0; half < 2; half++) {
        const unsigned short* srcb = (half == 0) ? self_bf : sbf;
        const unsigned short* p0 = srcb + (size_t)r0c * F + quad * 8;
        const unsigned short* p1 = srcb + (size_t)r1c * F + quad * 8;
        short8 Ah0[4], Ah1[4];
#pragma unroll
        for (int kk = 0; kk < 4; kk++) {
            Ah0[kk] = *(const short8*)(p0 + kk * 32);
            Ah1[kk] = *(const short8*)(p1 + kk * 32);
        }
#pragma unroll
        for (int kk = 0; kk < 4; kk++) {
#pragma unroll
            for (int ct = 0; ct < 8; ct++) {
                int r = ct * 16 + lane16;
                int col = half * 128 + kk * 32 + quad * 8;
                short8 b = *(const short8*)(lbase + (size_t)r * 256 + (col ^ swz));
                acc0[ct] = __builtin_amdgcn_mfma_f32_16x16x32_bf16(Ah0[kk], b, acc0[ct], 0, 0, 0);
                acc1[ct] = __builtin_amdgcn_mfma_f32_16x16x32_bf16(Ah1[kk], b, acc1[ct], 0, 0, 0);
            }
        }
    }

    int rowb0 = base + w * 32 + quad * 4;
    int rowb1 = rowb0 + 16;
#pragma unroll
    for (int ct = 0; ct < 8; ct++) {
        int col = ct * 16 + lane16;
        float bc = bias[col];
#pragma unroll
        for (int r = 0; r < 4; r++) {
            int g0 = rowb0 + r, g1 = rowb1 + r;
            float v0 = acc0[ct][r] + bc;
            float v1 = acc1[ct][r] + bc;
            if (out_bf) {
                v0 = fmaxf(v0, 0.0f);
                v1 = fmaxf(v1, 0.0f);
                if (g0 < NN) out_bf[(size_t)g0 * F + col] = (unsigned short)f2bf(v0);
                if (g1 < NN) out_bf[(size_t)g1 * F + col] = (unsigned short)f2bf(v1);
            } else {
                if (g0 < NN) out_f32[(size_t)g0 * F + col] = v0;
                if (g1 < NN) out_f32[(size_t)g1 * F + col] = v1;
            }
        }
    }
}

// ======================= fallback (f32 atomic path) =======================

__global__ __launch_bounds__(256) void scatter_kernel(const float* __restrict__ h,
                                                      const float* __restrict__ w,
                                                      const int* __restrict__ src,
                                                      const int* __restrict__ dst,
                                                      float* __restrict__ s,
                                                      float* __restrict__ deg,
                                                      int add_deg) {
    int e = blockIdx.x * 4 + (threadIdx.x >> 6);
    int lane = threadIdx.x & 63;
    int sn = src[e];
    int dn = dst[e];
    float wf = w[e];
    float2 p = *(const float2*)(h + (size_t)sn * F + lane * 2);
    float* sp = s + (size_t)dn * F + lane * 2;
    unsafeAtomicAdd(sp,     wf * p.x);
    unsafeAtomicAdd(sp + 1, wf * p.y);
    if (add_deg && lane == 0) unsafeAtomicAdd(&deg[dn], 1.0f);
}

__global__ __launch_bounds__(256) void sage_gemm(const float* h,
                                                 const float* __restrict__ s,
                                                 const float* deg,
                                                 const float* __restrict__ Ws,
                                                 const float* __restrict__ bias,
                                                 const float* __restrict__ Wn,
                                                 float* out,
                                                 int relu) {
    __shared__ float xs[16][F];
    __shared__ float invd[16];
    int t = threadIdx.x;
    int j = t & 127;
    int g = t >> 7;
    int base = blockIdx.x * 16;
    for (int idx = t; idx < 16 * 32; idx += 256) {
        int n = idx >> 5, kq = idx & 31;
        *(float4*)&xs[n][kq * 4] = *(const float4*)(h + (size_t)(base + n) * F + kq * 4);
    }
    if (t < 16) invd[t] = deg ? 1.0f / fmaxf(deg[base + t], 1.0f) : 1.0f;
    __syncthreads();
    float acc[8];
#pragma unroll
    for (int i = 0; i < 8; i++) acc[i] = 0.0f;
    for (int kc = 0; kc < F; kc += 4) {
        float4 wv = *(const float4*)(Ws + j * F + kc);
#pragma unroll
        for (int i = 0; i < 8; i++) {
            const float* xr = &xs[g * 8 + i][kc];
            acc[i] += xr[0] * wv.x + xr[1] * wv.y + xr[2] * wv.z + xr[3] * wv.w;
        }
    }
    __syncthreads();
    for (int idx = t; idx < 16 * 32; idx += 256) {
        int n = idx >> 5, kq = idx & 31;
        float4 sv = *(const float4*)(s + (size_t)(base + n) * F + kq * 4);
        float iv = invd[n];
        xs[n][kq * 4]     = sv.x * iv;
        xs[n][kq * 4 + 1] = sv.y * iv;
        xs[n][kq * 4 + 2] = sv.z * iv;
        xs[n][kq * 4 + 3] = sv.w * iv;
    }
    __syncthreads();
    for (int kc = 0; kc < F; kc += 4) {
        float4 wv = *(const float4*)(Wn + j * F + kc);
#pragma unroll
        for (int i = 0; i < 8; i++) {
            const float* xr = &xs[g * 8 + i][kc];
            acc[i] += xr[0] * wv.x + xr[1] * wv.y + xr[2] * wv.z + xr[3] * wv.w;
        }
    }
    float bj = bias[j];
#pragma unroll
    for (int i = 0; i < 8; i++) {
        int n = base + g * 8 + i;
        float v = acc[i] + bj;
        if (relu) v = fmaxf(v, 0.0f);
        out[(size_t)n * F + j] = v;
    }
}

extern "C" void kernel_launch(void* const* d_in, const int* in_sizes, int n_in,
                              void* d_out, int out_size, void* d_ws, size_t ws_size,
                              hipStream_t stream) {
    const float* in_feat = (const float*)d_in[0];
    const float* weights = (const float*)d_in[1];
    const int* src = (const int*)d_in[2];
    const int* dst = (const int*)d_in[3];
    const float* Ws1 = (const float*)d_in[4];
    const float* b1  = (const float*)d_in[5];
    const float* Wn1 = (const float*)d_in[6];
    const float* Ws2 = (const float*)d_in[7];
    const float* b2  = (const float*)d_in[8];
    const float* Wn2 = (const float*)d_in[9];
    float* out = (float*)d_out;

    if (ws_size >= WS_NEED) {
        int* bbase  = (int*)((char*)d_ws + BBASE_OFF);
        int* bcur   = (int*)((char*)d_ws + BCUR_OFF);
        int* bcnt   = (int*)((char*)d_ws + BCNT_OFF);
        int* row    = (int*)((char*)d_ws + ROW_OFF);
        int2* edge  = (int2*)((char*)d_ws + EDGE_OFF);
        unsigned short* wcat1 = (unsigned short*)((char*)d_ws + WCAT1_OFF);
        unsigned short* wcat2 = (unsigned short*)((char*)d_ws + WCAT2_OFF);
        unsigned short* sbf   = (unsigned short*)((char*)d_ws + SBF_OFF);
        int2* ebuf  = (int2*)((char*)d_ws + SBF_OFF);   // aliases sbf (dead until gather1)
        unsigned short* hbf   = (unsigned short*)((char*)d_ws + H1BF_OFF); // infbf -> h1bf

        hipMemsetAsync(bcnt, 0, NBUK * sizeof(int), stream);
        bcount_kernel<<<NBLK2, 256, 0, stream>>>(dst, bcnt);
        bscan_kernel<<<1, 256, 0, stream>>>(bcnt, bbase, bcur);
        bscatter<<<NBLK3, 256, 0, stream>>>(src, dst, weights, bcur, ebuf);
        fine_fill2<<<NBUK, 256, 0, stream>>>(bbase, ebuf, row, edge);
        prep_kernel<<<CONV_BLOCKS + 256, 256, 0, stream>>>(in_feat, hbf,
                                                           Ws1, Wn1, Ws2, Wn2,
                                                           wcat1, wcat2);

        // layer 1 (gemm1 in-place over hbf: infbf -> h1bf)
        gather_packed<<<NN / 4, 256, 0, stream>>>(hbf, row, edge, sbf);
        mfma_gemm<<<(NN + 255) / 256, 512, 0, stream>>>(hbf, sbf, wcat1, b1, hbf, nullptr);
        // layer 2
        gather_packed<<<NN / 4, 256, 0, stream>>>(hbf, row, edge, sbf);
        mfma_gemm<<<(NN + 255) / 256, 512, 0, stream>>>(hbf, sbf, wcat2, b2, nullptr, out);
    } else {
        float* deg = (float*)d_ws;
        float* s   = (float*)((char*)d_ws + FB_S_OFF);
        hipMemsetAsync(d_ws, 0, FB_S_OFF + (size_t)NN * F * 4, stream);
        scatter_kernel<<<NE / 4, 256, 0, stream>>>(in_feat, weights, src, dst, s, deg, 1);
        sage_gemm<<<NN / 16, 256, 0, stream>>>(in_feat, s, deg, Ws1, b1, Wn1, out, 1);
        hipMemsetAsync(s, 0, (size_t)NN * F * 4, stream);
        scatter_kernel<<<NE / 4, 256, 0, stream>>>(out, weights, src, dst, s, deg, 0);
        sage_gemm<<<NN / 16, 256, 0, stream>>>(out, s, deg, Ws2, b2, Wn2, out, 0);
    }
}